// Round 9
// baseline (384.000 us; speedup 1.0000x reference)
//
#include <hip/hip_runtime.h>
#include <hip/hip_bf16.h>

// GatedMoE: B=8, T=4096, D=128, E=16, TOP_K=2 (f32 in/out, bf16 MFMA inside)
// out = concat(weighted_avg [NTOK*128] f32, consensus [NTOK] f32)
// R9 = R8 pipeline with combine FUSED into the expert kernel via a per-token
// done-flag handshake (device-scope fences per Guideline 16). 4 graph nodes.
#define NTOK 32768
#define DD 128
#define NE 16
#define CSTRIDE 32   // pad each expert counter to its own 128B line

// ws layout (bytes); total 28 MiB
#define OFF_COUNTS 0                     // NE*CSTRIDE ints = 2 KiB
#define OFF_DONE   (4*1024)              // NTOK ints = 128 KiB (memset w/ counts)
#define OFF_TOKW   (256*1024)            // NTOK*2 f32  = 256 KiB
#define OFF_LISTS  (512*1024)            // NE*NTOK int = 2 MiB
#define OFF_XB     (3*1024*1024)         // NTOK*128 bf16 = 8 MiB
#define OFF_EWT    (11*1024*1024)        // NE*128*128 bf16 = 512 KiB
#define OFF_YBUF   (12*1024*1024)        // NTOK*2*128 bf16 = 16 MiB

typedef __attribute__((ext_vector_type(8))) short bf16x8;
typedef __attribute__((ext_vector_type(4))) float f32x4;

static __device__ inline ushort f2bf(float f) {      // RNE f32 -> bf16 bits
    uint u = __builtin_bit_cast(uint, f);
    u = u + 0x7FFFu + ((u >> 16) & 1u);
    return (ushort)(u >> 16);
}
static __device__ inline float b2f(ushort h) {
    uint u = ((uint)h) << 16;
    return __builtin_bit_cast(float, u);
}

// ---------------- Kernel 0: Ew f32[k][o] -> EwT bf16[o][k] ------------------
// grid = 256 blocks (16 experts x 16 tiles of 32x32), 256 threads. (validated)
__global__ __launch_bounds__(256) void ewt_kernel(
    const float* __restrict__ Ew, ushort* __restrict__ ewT)
{
    __shared__ float tile[32][33];
    const int b = blockIdx.x;
    const int e = b >> 4, ki = ((b >> 2) & 3) * 32, oi = (b & 3) * 32;
    const int tid = threadIdx.x;
    const int r = tid >> 3, c4 = (tid & 7) * 4;
    const float4 v = *(const float4*)(Ew + (size_t)e * DD * DD + (ki + r) * DD + oi + c4);
    tile[r][c4 + 0] = v.x; tile[r][c4 + 1] = v.y;
    tile[r][c4 + 2] = v.z; tile[r][c4 + 3] = v.w;
    __syncthreads();
    const int o = tid >> 3, k4 = (tid & 7) * 4;
    ushort4 s;
    s.x = f2bf(tile[k4 + 0][o]);
    s.y = f2bf(tile[k4 + 1][o]);
    s.z = f2bf(tile[k4 + 2][o]);
    s.w = f2bf(tile[k4 + 3][o]);
    *(ushort4*)(ewT + (size_t)e * DD * DD + (oi + o) * DD + ki + k4) = s;
}

// ---------------- Kernel 1: gating + x->bf16 + per-expert lists --------------
// 4 lanes per token; 256 thr = 64 tokens/block; grid 512. (validated R8)
__global__ __launch_bounds__(256) void gate_kernel(
    const float* __restrict__ x, const float* __restrict__ Wg,
    const float* __restrict__ bg,
    int* __restrict__ counts, int* __restrict__ lists, float* __restrict__ tokw,
    ushort* __restrict__ xb)
{
    __shared__ float sWgT[NE][DD];   // 8 KiB, expert-major
    __shared__ float sBg[NE];
    __shared__ int   sCnt[NE];
    __shared__ int   sBase[NE];
    const int tid = threadIdx.x;
    for (int i = tid; i < DD * NE; i += 256) {
        int d = i & 127, e = i >> 7;
        sWgT[e][d] = Wg[d * NE + e];
    }
    if (tid < NE) { sBg[tid] = bg[tid]; sCnt[tid] = 0; }
    __syncthreads();

    const int t = blockIdx.x * 64 + (tid >> 2);
    const int g = tid & 3;
    const float* xt = x + (size_t)t * DD;
    ushort*      xo = xb + (size_t)t * DD;

    float logits[NE];
    #pragma unroll
    for (int e = 0; e < NE; ++e) logits[e] = 0.0f;

    #pragma unroll
    for (int i = 0; i < 8; ++i) {
        const int d0 = g * 4 + i * 16;
        float4 v = ((const float4*)xt)[g + i * 4];
        #pragma unroll
        for (int e = 0; e < NE; ++e) {
            float4 w4 = *(const float4*)&sWgT[e][d0];
            float a = logits[e];
            a = fmaf(v.x, w4.x, a);
            a = fmaf(v.y, w4.y, a);
            a = fmaf(v.z, w4.z, a);
            a = fmaf(v.w, w4.w, a);
            logits[e] = a;
        }
        ushort4 s; s.x = f2bf(v.x); s.y = f2bf(v.y); s.z = f2bf(v.z); s.w = f2bf(v.w);
        *(ushort4*)(xo + d0) = s;
    }

    #pragma unroll
    for (int e = 0; e < NE; ++e) {
        float a = logits[e];
        a += __shfl_xor(a, 1);
        a += __shfl_xor(a, 2);
        logits[e] = a + sBg[e];
    }

    float m = logits[0];
    #pragma unroll
    for (int e = 1; e < NE; ++e) m = fmaxf(m, logits[e]);
    float Z = 0.0f;
    #pragma unroll
    for (int e = 0; e < NE; ++e) Z += expf(logits[e] - m);

    int i1 = 0; float l1 = logits[0];
    #pragma unroll
    for (int e = 1; e < NE; ++e) if (logits[e] > l1) { l1 = logits[e]; i1 = e; }
    int i2 = -1; float l2 = -3.4e38f;
    #pragma unroll
    for (int e = 0; e < NE; ++e) if (e != i1 && logits[e] > l2) { l2 = logits[e]; i2 = e; }

    int s1 = 0, s2 = 0;
    if (g == 0) {
        float p1 = expf(l1 - m) / Z;
        float p2 = expf(l2 - m) / Z;
        float s  = p1 + p2 + 1e-6f;
        tokw[t * 2 + 0] = p1 / s;
        tokw[t * 2 + 1] = p2 / s;
        s1 = atomicAdd(&sCnt[i1], 1);
        s2 = atomicAdd(&sCnt[i2], 1);
    }
    __syncthreads();
    if (tid < NE) sBase[tid] = atomicAdd(&counts[tid * CSTRIDE], sCnt[tid]);
    __syncthreads();
    if (g == 0) {
        lists[i1 * NTOK + sBase[i1] + s1] = t * 2 + 0;
        lists[i2 * NTOK + sBase[i2] + s2] = t * 2 + 1;
    }
}

// ---------------- Kernel 2: expert GEMM + fused combine ----------------------
// grid (NTOK/64, NE), block 256 = 4 waves; wave = 16 tokens x 128 outputs.
// GEMM body identical to validated R8. Epilogue: write own y (bf16) ->
// release fence -> done-flag atomic; SECOND finisher acquires, reads other
// slot's y, and computes avg (own y in f32 regs) + var + consensus.
__global__ __launch_bounds__(256) void expert_kernel(
    const ushort* __restrict__ xb, const ushort* __restrict__ ewT,
    const int* __restrict__ counts, const int* __restrict__ lists,
    const float* __restrict__ tokw,
    ushort* __restrict__ ybuf, int* __restrict__ done,
    float* __restrict__ avg_out, float* __restrict__ cons_out)
{
    const int e = blockIdx.y;
    const int count = counts[e * CSTRIDE];
    const int start = blockIdx.x * 64;
    if (start >= count) return;

    const int tid  = threadIdx.x;
    const int lane = tid & 63, wv = tid >> 6;
    const int row  = lane & 15;          // token within wave tile == D column
    const int kg   = lane >> 4;          // k-group 0..3

    const int idx = start + wv * 16 + row;
    const int en  = (idx < count) ? lists[e * NTOK + idx] : -1;
    const ushort* xrow = xb + (size_t)((en < 0 ? 0 : en) >> 1) * DD;

    bf16x8 xf[4];
    #pragma unroll
    for (int k = 0; k < 4; ++k)
        xf[k] = *(const bf16x8*)(xrow + k * 32 + kg * 8);

    const ushort* ewe = ewT + (size_t)e * DD * DD;
    f32x4 acc[8];
    #pragma unroll
    for (int n = 0; n < 8; ++n) acc[n] = (f32x4)(0.0f);

    #pragma unroll
    for (int n = 0; n < 8; ++n) {
        const ushort* er = ewe + (size_t)(n * 16 + row) * DD + kg * 8;
        #pragma unroll
        for (int k = 0; k < 4; ++k) {
            bf16x8 ef = *(const bf16x8*)(er + k * 32);
            acc[n] = __builtin_amdgcn_mfma_f32_16x16x32_bf16(ef, xf[k], acc[n], 0, 0, 0);
        }
    }

    if (en >= 0) {
        ushort* yr = ybuf + (size_t)en * DD + kg * 4;   // o = n*16 + kg*4 + reg
        #pragma unroll
        for (int n = 0; n < 8; ++n) {
            ushort4 s;
            s.x = f2bf(acc[n][0]); s.y = f2bf(acc[n][1]);
            s.z = f2bf(acc[n][2]); s.w = f2bf(acc[n][3]);
            *(ushort4*)(yr + n * 16) = s;
        }
    }

    // release: make y visible device-wide before signalling
    __threadfence();
    int old = 0;
    if (en >= 0 && kg == 0) old = atomicAdd(&done[en >> 1], 1);
    old = __shfl(old, row);              // broadcast from lane (kg=0,row)

    if (en >= 0 && old == 1) {           // second finisher combines
        __threadfence();                 // acquire: see other slot's y
        const int t     = en >> 1;
        const int other = en ^ 1;
        const int sb    = en & 1;
        const float w_own = tokw[t * 2 + sb];
        const float w_oth = tokw[t * 2 + (sb ^ 1)];
        const ushort* yo = ybuf + (size_t)other * DD + kg * 4;

        float v = 0.0f;
        #pragma unroll
        for (int n = 0; n < 8; ++n) {
            ushort4 ro = *(const ushort4*)(yo + n * 16);
            float o0 = b2f(ro.x), o1 = b2f(ro.y), o2 = b2f(ro.z), o3 = b2f(ro.w);
            float a0 = w_own * acc[n][0] + w_oth * o0;
            float a1 = w_own * acc[n][1] + w_oth * o1;
            float a2 = w_own * acc[n][2] + w_oth * o2;
            float a3 = w_own * acc[n][3] + w_oth * o3;
            float4 av; av.x = a0; av.y = a1; av.z = a2; av.w = a3;
            *(float4*)(avg_out + (size_t)t * DD + n * 16 + kg * 4) = av;
            float d0 = acc[n][0] - a0, d1 = acc[n][1] - a1;
            float d2 = acc[n][2] - a2, d3 = acc[n][3] - a3;
            float e0 = o0 - a0, e1 = o1 - a1, e2 = o2 - a2, e3 = o3 - a3;
            v = fmaf(w_own, d0*d0 + d1*d1 + d2*d2 + d3*d3,
                fmaf(w_oth, e0*e0 + e1*e1 + e2*e2 + e3*e3, v));
        }
        // sum variance over the 4 kg-lanes of the same token
        v += __shfl_xor(v, 16);
        v += __shfl_xor(v, 32);
        if (kg == 0) cons_out[t] = expf(-v * (1.0f / 128.0f));
    }
}

// ---------------- launcher ---------------------------------------------------
extern "C" void kernel_launch(void* const* d_in, const int* in_sizes, int n_in,
                              void* d_out, int out_size, void* d_ws, size_t ws_size,
                              hipStream_t stream)
{
    const float* x  = (const float*)d_in[0];
    const float* Wg = (const float*)d_in[1];
    const float* bg = (const float*)d_in[2];
    const float* Ew = (const float*)d_in[3];
    float* out = (float*)d_out;

    char* ws = (char*)d_ws;
    int*    counts = (int*)(ws + OFF_COUNTS);
    int*    done   = (int*)(ws + OFF_DONE);
    float*  tokw   = (float*)(ws + OFF_TOKW);
    int*    lists  = (int*)(ws + OFF_LISTS);
    ushort* xbuf   = (ushort*)(ws + OFF_XB);
    ushort* ewT    = (ushort*)(ws + OFF_EWT);
    ushort* ybuf   = (ushort*)(ws + OFF_YBUF);

    // one memset node covers counts (2 KiB @0) and done (128 KiB @4 KiB)
    hipMemsetAsync(ws, 0, OFF_DONE + NTOK * sizeof(int), stream);

    ewt_kernel<<<256, 256, 0, stream>>>(Ew, ewT);
    gate_kernel<<<NTOK / 64, 256, 0, stream>>>(x, Wg, bg, counts, lists, tokw, xbuf);
    expert_kernel<<<dim3(NTOK / 64, NE), 256, 0, stream>>>(
        xbuf, ewT, counts, lists, tokw, ybuf, done,
        out, out + (size_t)NTOK * DD);
}

// Round 11
// 119.871 us; speedup vs baseline: 3.2034x; 3.2034x over previous
//
#include <hip/hip_runtime.h>
#include <hip/hip_bf16.h>

// GatedMoE: B=8, T=4096, D=128, E=16, TOP_K=2 (f32 in/out, bf16 MFMA inside)
// out = concat(weighted_avg [NTOK*128] f32, consensus [NTOK] f32)
// R11 = validated R8 pipeline, memset node folded into ewt_kernel (4 nodes).
#define NTOK 32768
#define DD 128
#define NE 16
#define CSTRIDE 32   // pad each expert counter to its own 128B line

// ws layout (bytes); total 28 MiB
#define OFF_COUNTS 0                     // NE*CSTRIDE ints = 2 KiB (zeroed by ewt)
#define OFF_TOKW   (4*1024)              // NTOK*2 f32  = 256 KiB
#define OFF_LISTS  (512*1024)            // NE*NTOK int = 2 MiB
#define OFF_XB     (3*1024*1024)         // NTOK*128 bf16 = 8 MiB
#define OFF_EWT    (11*1024*1024)        // NE*128*128 bf16 = 512 KiB
#define OFF_YBUF   (12*1024*1024)        // NTOK*2*128 bf16 = 16 MiB

typedef __attribute__((ext_vector_type(8))) short bf16x8;
typedef __attribute__((ext_vector_type(4))) float f32x4;

static __device__ inline ushort f2bf(float f) {      // RNE f32 -> bf16 bits
    uint u = __builtin_bit_cast(uint, f);
    u = u + 0x7FFFu + ((u >> 16) & 1u);
    return (ushort)(u >> 16);
}
static __device__ inline float b2f(ushort h) {
    uint u = ((uint)h) << 16;
    return __builtin_bit_cast(float, u);
}

// ---------------- Kernel 0: Ew f32[k][o] -> EwT bf16[o][k]  (+zero counts) --
// grid = 256 blocks (16 experts x 16 tiles of 32x32), 256 threads. (validated)
// Block 0 additionally zeroes the 512 padded pair counters; stream order
// guarantees this completes before gate_kernel's atomics.
__global__ __launch_bounds__(256) void ewt_kernel(
    const float* __restrict__ Ew, ushort* __restrict__ ewT,
    int* __restrict__ counts)
{
    __shared__ float tile[32][33];
    const int b = blockIdx.x;
    const int tid = threadIdx.x;
    if (b == 0) {                         // 512 ints = NE*CSTRIDE
        counts[tid * 2 + 0] = 0;
        counts[tid * 2 + 1] = 0;
    }
    const int e = b >> 4, ki = ((b >> 2) & 3) * 32, oi = (b & 3) * 32;
    const int r = tid >> 3, c4 = (tid & 7) * 4;
    const float4 v = *(const float4*)(Ew + (size_t)e * DD * DD + (ki + r) * DD + oi + c4);
    tile[r][c4 + 0] = v.x; tile[r][c4 + 1] = v.y;
    tile[r][c4 + 2] = v.z; tile[r][c4 + 3] = v.w;
    __syncthreads();
    const int o = tid >> 3, k4 = (tid & 7) * 4;
    ushort4 s;
    s.x = f2bf(tile[k4 + 0][o]);
    s.y = f2bf(tile[k4 + 1][o]);
    s.z = f2bf(tile[k4 + 2][o]);
    s.w = f2bf(tile[k4 + 3][o]);
    *(ushort4*)(ewT + (size_t)e * DD * DD + (oi + o) * DD + ki + k4) = s;
}

// ---------------- Kernel 1: gating + x->bf16 + per-expert lists --------------
// 4 lanes per token; 256 thr = 64 tokens/block; grid 512. (validated R8)
__global__ __launch_bounds__(256) void gate_kernel(
    const float* __restrict__ x, const float* __restrict__ Wg,
    const float* __restrict__ bg,
    int* __restrict__ counts, int* __restrict__ lists, float* __restrict__ tokw,
    ushort* __restrict__ xb)
{
    __shared__ float sWgT[NE][DD];   // 8 KiB, expert-major
    __shared__ float sBg[NE];
    __shared__ int   sCnt[NE];
    __shared__ int   sBase[NE];
    const int tid = threadIdx.x;
    for (int i = tid; i < DD * NE; i += 256) {
        int d = i & 127, e = i >> 7;
        sWgT[e][d] = Wg[d * NE + e];
    }
    if (tid < NE) { sBg[tid] = bg[tid]; sCnt[tid] = 0; }
    __syncthreads();

    const int t = blockIdx.x * 64 + (tid >> 2);
    const int g = tid & 3;
    const float* xt = x + (size_t)t * DD;
    ushort*      xo = xb + (size_t)t * DD;

    float logits[NE];
    #pragma unroll
    for (int e = 0; e < NE; ++e) logits[e] = 0.0f;

    #pragma unroll
    for (int i = 0; i < 8; ++i) {
        const int d0 = g * 4 + i * 16;
        float4 v = ((const float4*)xt)[g + i * 4];
        #pragma unroll
        for (int e = 0; e < NE; ++e) {
            float4 w4 = *(const float4*)&sWgT[e][d0];
            float a = logits[e];
            a = fmaf(v.x, w4.x, a);
            a = fmaf(v.y, w4.y, a);
            a = fmaf(v.z, w4.z, a);
            a = fmaf(v.w, w4.w, a);
            logits[e] = a;
        }
        ushort4 s; s.x = f2bf(v.x); s.y = f2bf(v.y); s.z = f2bf(v.z); s.w = f2bf(v.w);
        *(ushort4*)(xo + d0) = s;
    }

    // butterfly-sum partial logits over the 4-lane quad
    #pragma unroll
    for (int e = 0; e < NE; ++e) {
        float a = logits[e];
        a += __shfl_xor(a, 1);
        a += __shfl_xor(a, 2);
        logits[e] = a + sBg[e];
    }

    float m = logits[0];
    #pragma unroll
    for (int e = 1; e < NE; ++e) m = fmaxf(m, logits[e]);
    float Z = 0.0f;
    #pragma unroll
    for (int e = 0; e < NE; ++e) Z += expf(logits[e] - m);

    int i1 = 0; float l1 = logits[0];
    #pragma unroll
    for (int e = 1; e < NE; ++e) if (logits[e] > l1) { l1 = logits[e]; i1 = e; }
    int i2 = -1; float l2 = -3.4e38f;
    #pragma unroll
    for (int e = 0; e < NE; ++e) if (e != i1 && logits[e] > l2) { l2 = logits[e]; i2 = e; }

    int s1 = 0, s2 = 0;
    if (g == 0) {
        float p1 = expf(l1 - m) / Z;
        float p2 = expf(l2 - m) / Z;
        float s  = p1 + p2 + 1e-6f;
        tokw[t * 2 + 0] = p1 / s;
        tokw[t * 2 + 1] = p2 / s;
        s1 = atomicAdd(&sCnt[i1], 1);
        s2 = atomicAdd(&sCnt[i2], 1);
    }
    __syncthreads();
    if (tid < NE) sBase[tid] = atomicAdd(&counts[tid * CSTRIDE], sCnt[tid]);
    __syncthreads();
    if (g == 0) {
        lists[i1 * NTOK + sBase[i1] + s1] = t * 2 + 0;
        lists[i2 * NTOK + sBase[i2] + s2] = t * 2 + 1;
    }
}

// ---------------- Kernel 2: grouped expert GEMM via bf16 MFMA ----------------
// grid (NTOK/64, NE), block 256 = 4 waves; wave = 16 tokens x 128 outputs.
// No LDS, no barriers (validated R4/R8: 68 VGPR, high occupancy).
__global__ __launch_bounds__(256) void expert_kernel(
    const ushort* __restrict__ xb, const ushort* __restrict__ ewT,
    const int* __restrict__ counts, const int* __restrict__ lists,
    ushort* __restrict__ ybuf)
{
    const int e = blockIdx.y;
    const int count = counts[e * CSTRIDE];
    const int start = blockIdx.x * 64;
    if (start >= count) return;

    const int tid  = threadIdx.x;
    const int lane = tid & 63, wv = tid >> 6;
    const int row  = lane & 15;          // token within wave tile == D column
    const int kg   = lane >> 4;          // k-group 0..3

    const int idx = start + wv * 16 + row;
    const int en  = (idx < count) ? lists[e * NTOK + idx] : -1;
    const ushort* xrow = xb + (size_t)((en < 0 ? 0 : en) >> 1) * DD;

    bf16x8 xf[4];
    #pragma unroll
    for (int k = 0; k < 4; ++k)
        xf[k] = *(const bf16x8*)(xrow + k * 32 + kg * 8);

    const ushort* ewe = ewT + (size_t)e * DD * DD;
    f32x4 acc[8];
    #pragma unroll
    for (int n = 0; n < 8; ++n) acc[n] = (f32x4)(0.0f);

    #pragma unroll
    for (int n = 0; n < 8; ++n) {
        const ushort* er = ewe + (size_t)(n * 16 + row) * DD + kg * 8;
        #pragma unroll
        for (int k = 0; k < 4; ++k) {
            bf16x8 ef = *(const bf16x8*)(er + k * 32);
            acc[n] = __builtin_amdgcn_mfma_f32_16x16x32_bf16(ef, xf[k], acc[n], 0, 0, 0);
        }
    }

    if (en >= 0) {
        ushort* yr = ybuf + (size_t)en * DD + kg * 4;   // o = n*16 + kg*4 + reg
        #pragma unroll
        for (int n = 0; n < 8; ++n) {
            ushort4 s;
            s.x = f2bf(acc[n][0]); s.y = f2bf(acc[n][1]);
            s.z = f2bf(acc[n][2]); s.w = f2bf(acc[n][3]);
            *(ushort4*)(yr + n * 16) = s;
        }
    }
}

// ---------------- Kernel 3: combine (avg, var, consensus) -------------------
// block 256 = 4 waves; wave does 4 tokens. Lanes 0-31 load y1 (ushort4 dims),
// lanes 32-63 load y2; shfl_xor(32) exchange; coalesced float4 avg store.
// (validated R4/R8)
__global__ __launch_bounds__(256) void combine_kernel(
    const ushort* __restrict__ ybuf, const float* __restrict__ tokw,
    float* __restrict__ avg_out, float* __restrict__ cons_out)
{
    const int tid = threadIdx.x;
    const int lane = tid & 63, wv = tid >> 6;
    const int half = lane >> 5, hl = lane & 31;
    const int t0 = blockIdx.x * 16 + wv * 4;

    #pragma unroll
    for (int j = 0; j < 4; ++j) {
        const int t = t0 + j;
        const float w1 = tokw[t * 2 + 0];
        const float w2 = tokw[t * 2 + 1];
        const float wo = half ? w2 : w1;
        const float wx = half ? w1 : w2;

        ushort4 raw = *(const ushort4*)(ybuf + (size_t)(t * 2 + half) * DD + hl * 4);
        float o0 = b2f(raw.x), o1 = b2f(raw.y), o2 = b2f(raw.z), o3 = b2f(raw.w);
        float x0 = __shfl_xor(o0, 32);
        float x1 = __shfl_xor(o1, 32);
        float x2 = __shfl_xor(o2, 32);
        float x3 = __shfl_xor(o3, 32);

        float a0 = wo * o0 + wx * x0;
        float a1 = wo * o1 + wx * x1;
        float a2 = wo * o2 + wx * x2;
        float a3 = wo * o3 + wx * x3;
        if (half == 0) {
            float4 av; av.x = a0; av.y = a1; av.z = a2; av.w = a3;
            ((float4*)(avg_out + (size_t)t * DD))[hl] = av;
        }
        float d0 = o0 - a0, d1 = o1 - a1, d2 = o2 - a2, d3 = o3 - a3;
        float e0 = x0 - a0, e1 = x1 - a1, e2 = x2 - a2, e3 = x3 - a3;
        float v = wo * (d0*d0 + d1*d1 + d2*d2 + d3*d3)
                + wx * (e0*e0 + e1*e1 + e2*e2 + e3*e3);
        v += __shfl_xor(v, 1);
        v += __shfl_xor(v, 2);
        v += __shfl_xor(v, 4);
        v += __shfl_xor(v, 8);
        v += __shfl_xor(v, 16);
        if (lane == 0) cons_out[t] = expf(-v * (1.0f / 128.0f));
    }
}

// ---------------- launcher ---------------------------------------------------
extern "C" void kernel_launch(void* const* d_in, const int* in_sizes, int n_in,
                              void* d_out, int out_size, void* d_ws, size_t ws_size,
                              hipStream_t stream)
{
    const float* x  = (const float*)d_in[0];
    const float* Wg = (const float*)d_in[1];
    const float* bg = (const float*)d_in[2];
    const float* Ew = (const float*)d_in[3];
    float* out = (float*)d_out;

    char* ws = (char*)d_ws;
    int*    counts = (int*)(ws + OFF_COUNTS);
    float*  tokw   = (float*)(ws + OFF_TOKW);
    int*    lists  = (int*)(ws + OFF_LISTS);
    ushort* xbuf   = (ushort*)(ws + OFF_XB);
    ushort* ewT    = (ushort*)(ws + OFF_EWT);
    ushort* ybuf   = (ushort*)(ws + OFF_YBUF);

    ewt_kernel<<<256, 256, 0, stream>>>(Ew, ewT, counts);
    gate_kernel<<<NTOK / 64, 256, 0, stream>>>(x, Wg, bg, counts, lists, tokw, xbuf);
    expert_kernel<<<dim3(NTOK / 64, NE), 256, 0, stream>>>(xbuf, ewT, counts, lists, ybuf);
    combine_kernel<<<NTOK / 16, 256, 0, stream>>>(ybuf, tokw, out, out + (size_t)NTOK * DD);
}

// Round 12
// 108.568 us; speedup vs baseline: 3.5370x; 1.1041x over previous
//
#include <hip/hip_runtime.h>
#include <hip/hip_bf16.h>

// GatedMoE: B=8, T=4096, D=128, E=16, TOP_K=2 (f32 in/out, bf16 MFMA inside)
// out = concat(weighted_avg [NTOK*128] f32, consensus [NTOK] f32)
// R12: 3 nodes. No global counters: gate writes per-block segments + headers;
// expert compacts 16 segments in LDS. ewt+gate merged (independent halves).
#define NTOK 32768
#define DD 128
#define NE 16
#define NGBLK 512    // gate blocks (64 tokens each)
#define NSEG 16      // segments per expert block
// ws layout (bytes); total 28 MiB
#define OFF_HDR    0                     // NE*NGBLK ints = 32 KiB
#define OFF_TOKW   (64*1024)             // NTOK*2 f32  = 256 KiB
#define OFF_LISTS  (512*1024)            // NE*NTOK int = 2 MiB
#define OFF_XB     (3*1024*1024)         // NTOK*128 bf16 = 8 MiB
#define OFF_EWT    (11*1024*1024)        // NE*128*128 bf16 = 512 KiB
#define OFF_YBUF   (12*1024*1024)        // NTOK*2*128 bf16 = 16 MiB

typedef __attribute__((ext_vector_type(8))) short bf16x8;
typedef __attribute__((ext_vector_type(4))) float f32x4;

static __device__ inline ushort f2bf(float f) {      // RNE f32 -> bf16 bits
    uint u = __builtin_bit_cast(uint, f);
    u = u + 0x7FFFu + ((u >> 16) & 1u);
    return (ushort)(u >> 16);
}
static __device__ inline float b2f(ushort h) {
    uint u = ((uint)h) << 16;
    return __builtin_bit_cast(float, u);
}

// ---------------- Kernel 1: ewt (blocks 0-255) + gate (blocks 256-767) -------
// ewt: Ew f32[k][o] -> EwT bf16[o][k], validated body.
// gate: validated R8 body, but list build is per-block-segment (no global
// atomics): lists[e*NTOK + gbid*64 + slot], hdr[e*NGBLK + gbid] = cnt.
__global__ __launch_bounds__(256) void prep_kernel(
    const float* __restrict__ x, const float* __restrict__ Wg,
    const float* __restrict__ bg, const float* __restrict__ Ew,
    ushort* __restrict__ ewT, int* __restrict__ hdr, int* __restrict__ lists,
    float* __restrict__ tokw, ushort* __restrict__ xb)
{
    __shared__ __align__(16) float smem[NE * DD + NE];   // gate WgT+Bg; ewt 32x33 tile
    __shared__ int sCnt[NE];
    const int bid = blockIdx.x, tid = threadIdx.x;

    if (bid < 256) {
        // ---- ewt half (validated) ----
        float (*tile)[33] = (float(*)[33])smem;
        const int e = bid >> 4, ki = ((bid >> 2) & 3) * 32, oi = (bid & 3) * 32;
        const int r = tid >> 3, c4 = (tid & 7) * 4;
        const float4 v = *(const float4*)(Ew + (size_t)e * DD * DD + (ki + r) * DD + oi + c4);
        tile[r][c4 + 0] = v.x; tile[r][c4 + 1] = v.y;
        tile[r][c4 + 2] = v.z; tile[r][c4 + 3] = v.w;
        __syncthreads();
        const int o = tid >> 3, k4 = (tid & 7) * 4;
        ushort4 s;
        s.x = f2bf(tile[k4 + 0][o]);
        s.y = f2bf(tile[k4 + 1][o]);
        s.z = f2bf(tile[k4 + 2][o]);
        s.w = f2bf(tile[k4 + 3][o]);
        *(ushort4*)(ewT + (size_t)e * DD * DD + (oi + o) * DD + ki + k4) = s;
        return;
    }

    // ---- gate half (validated R8 math; segment list build) ----
    const int gbid = bid - 256;
    float (*sWgT)[DD] = (float(*)[DD])smem;
    float* sBg = smem + NE * DD;
    for (int i = tid; i < DD * NE; i += 256) {
        int d = i & 127, e = i >> 7;
        sWgT[e][d] = Wg[d * NE + e];
    }
    if (tid < NE) { sBg[tid] = bg[tid]; sCnt[tid] = 0; }
    __syncthreads();

    const int t = gbid * 64 + (tid >> 2);
    const int g = tid & 3;
    const float* xt = x + (size_t)t * DD;
    ushort*      xo = xb + (size_t)t * DD;

    float logits[NE];
    #pragma unroll
    for (int e = 0; e < NE; ++e) logits[e] = 0.0f;

    #pragma unroll
    for (int i = 0; i < 8; ++i) {
        const int d0 = g * 4 + i * 16;
        float4 v = ((const float4*)xt)[g + i * 4];
        #pragma unroll
        for (int e = 0; e < NE; ++e) {
            float4 w4 = *(const float4*)&sWgT[e][d0];
            float a = logits[e];
            a = fmaf(v.x, w4.x, a);
            a = fmaf(v.y, w4.y, a);
            a = fmaf(v.z, w4.z, a);
            a = fmaf(v.w, w4.w, a);
            logits[e] = a;
        }
        ushort4 s; s.x = f2bf(v.x); s.y = f2bf(v.y); s.z = f2bf(v.z); s.w = f2bf(v.w);
        *(ushort4*)(xo + d0) = s;
    }

    #pragma unroll
    for (int e = 0; e < NE; ++e) {
        float a = logits[e];
        a += __shfl_xor(a, 1);
        a += __shfl_xor(a, 2);
        logits[e] = a + sBg[e];
    }

    float m = logits[0];
    #pragma unroll
    for (int e = 1; e < NE; ++e) m = fmaxf(m, logits[e]);
    float Z = 0.0f;
    #pragma unroll
    for (int e = 0; e < NE; ++e) Z += expf(logits[e] - m);

    int i1 = 0; float l1 = logits[0];
    #pragma unroll
    for (int e = 1; e < NE; ++e) if (logits[e] > l1) { l1 = logits[e]; i1 = e; }
    int i2 = -1; float l2 = -3.4e38f;
    #pragma unroll
    for (int e = 0; e < NE; ++e) if (e != i1 && logits[e] > l2) { l2 = logits[e]; i2 = e; }

    if (g == 0) {
        float p1 = expf(l1 - m) / Z;
        float p2 = expf(l2 - m) / Z;
        float s  = p1 + p2 + 1e-6f;
        tokw[t * 2 + 0] = p1 / s;
        tokw[t * 2 + 1] = p2 / s;
        int s1 = atomicAdd(&sCnt[i1], 1);
        int s2 = atomicAdd(&sCnt[i2], 1);
        lists[i1 * NTOK + gbid * 64 + s1] = t * 2 + 0;
        lists[i2 * NTOK + gbid * 64 + s2] = t * 2 + 1;
    }
    __syncthreads();
    if (tid < NE) hdr[tid * NGBLK + gbid] = sCnt[tid];
}

// ---------------- Kernel 2: grouped expert GEMM via bf16 MFMA ----------------
// grid (NGBLK/NSEG=32, NE) = 512 blocks. Block compacts its 16 segments'
// entries into LDS, then runs the validated MFMA tile body per 64-entry tile.
__global__ __launch_bounds__(256) void expert_kernel(
    const ushort* __restrict__ xb, const ushort* __restrict__ ewT,
    const int* __restrict__ hdr, const int* __restrict__ lists,
    ushort* __restrict__ ybuf)
{
    const int e = blockIdx.y;
    const int sg = blockIdx.x;           // segment group: segments sg*16..+15
    __shared__ int sCnt16[NSEG];
    __shared__ int sEnt[NSEG * 64];      // capacity exact: 16 segs x <=64
    const int tid = threadIdx.x;

    if (tid < NSEG) sCnt16[tid] = hdr[e * NGBLK + sg * NSEG + tid];
    __syncthreads();

    int off[NSEG + 1];
    off[0] = 0;
    #pragma unroll
    for (int s = 0; s < NSEG; ++s) off[s + 1] = off[s] + sCnt16[s];
    const int C = off[NSEG];
    if (C == 0) return;

    #pragma unroll
    for (int s = 0; s < NSEG; ++s) {
        const int c = sCnt16[s];
        const int* src = lists + e * NTOK + (sg * NSEG + s) * 64;
        for (int i = tid; i < c; i += 256) sEnt[off[s] + i] = src[i];
    }
    __syncthreads();

    const int lane = tid & 63, wv = tid >> 6;
    const int row  = lane & 15;          // token within wave tile == D column
    const int kg   = lane >> 4;          // k-group 0..3
    const ushort* ewe = ewT + (size_t)e * DD * DD;

    for (int base = 0; base < C; base += 64) {
        const int idx = base + wv * 16 + row;
        const int en  = (idx < C) ? sEnt[idx] : -1;
        const ushort* xrow = xb + (size_t)((en < 0 ? 0 : en) >> 1) * DD;

        bf16x8 xf[4];
        #pragma unroll
        for (int k = 0; k < 4; ++k)
            xf[k] = *(const bf16x8*)(xrow + k * 32 + kg * 8);

        f32x4 acc[8];
        #pragma unroll
        for (int n = 0; n < 8; ++n) acc[n] = (f32x4)(0.0f);

        #pragma unroll
        for (int n = 0; n < 8; ++n) {
            const ushort* er = ewe + (size_t)(n * 16 + row) * DD + kg * 8;
            #pragma unroll
            for (int k = 0; k < 4; ++k) {
                bf16x8 ef = *(const bf16x8*)(er + k * 32);
                acc[n] = __builtin_amdgcn_mfma_f32_16x16x32_bf16(ef, xf[k], acc[n], 0, 0, 0);
            }
        }

        if (en >= 0) {
            ushort* yr = ybuf + (size_t)en * DD + kg * 4;   // o = n*16+kg*4+reg
            #pragma unroll
            for (int n = 0; n < 8; ++n) {
                ushort4 s;
                s.x = f2bf(acc[n][0]); s.y = f2bf(acc[n][1]);
                s.z = f2bf(acc[n][2]); s.w = f2bf(acc[n][3]);
                *(ushort4*)(yr + n * 16) = s;
            }
        }
    }
}

// ---------------- Kernel 3: combine (avg, var, consensus) -------------------
// (validated R4/R8) block 256 = 4 waves; wave does 4 tokens; half-wave split.
__global__ __launch_bounds__(256) void combine_kernel(
    const ushort* __restrict__ ybuf, const float* __restrict__ tokw,
    float* __restrict__ avg_out, float* __restrict__ cons_out)
{
    const int tid = threadIdx.x;
    const int lane = tid & 63, wv = tid >> 6;
    const int half = lane >> 5, hl = lane & 31;
    const int t0 = blockIdx.x * 16 + wv * 4;

    #pragma unroll
    for (int j = 0; j < 4; ++j) {
        const int t = t0 + j;
        const float w1 = tokw[t * 2 + 0];
        const float w2 = tokw[t * 2 + 1];
        const float wo = half ? w2 : w1;
        const float wx = half ? w1 : w2;

        ushort4 raw = *(const ushort4*)(ybuf + (size_t)(t * 2 + half) * DD + hl * 4);
        float o0 = b2f(raw.x), o1 = b2f(raw.y), o2 = b2f(raw.z), o3 = b2f(raw.w);
        float x0 = __shfl_xor(o0, 32);
        float x1 = __shfl_xor(o1, 32);
        float x2 = __shfl_xor(o2, 32);
        float x3 = __shfl_xor(o3, 32);

        float a0 = wo * o0 + wx * x0;
        float a1 = wo * o1 + wx * x1;
        float a2 = wo * o2 + wx * x2;
        float a3 = wo * o3 + wx * x3;
        if (half == 0) {
            float4 av; av.x = a0; av.y = a1; av.z = a2; av.w = a3;
            ((float4*)(avg_out + (size_t)t * DD))[hl] = av;
        }
        float d0 = o0 - a0, d1 = o1 - a1, d2 = o2 - a2, d3 = o3 - a3;
        float e0 = x0 - a0, e1 = x1 - a1, e2 = x2 - a2, e3 = x3 - a3;
        float v = wo * (d0*d0 + d1*d1 + d2*d2 + d3*d3)
                + wx * (e0*e0 + e1*e1 + e2*e2 + e3*e3);
        v += __shfl_xor(v, 1);
        v += __shfl_xor(v, 2);
        v += __shfl_xor(v, 4);
        v += __shfl_xor(v, 8);
        v += __shfl_xor(v, 16);
        if (lane == 0) cons_out[t] = expf(-v * (1.0f / 128.0f));
    }
}

// ---------------- launcher ---------------------------------------------------
extern "C" void kernel_launch(void* const* d_in, const int* in_sizes, int n_in,
                              void* d_out, int out_size, void* d_ws, size_t ws_size,
                              hipStream_t stream)
{
    const float* x  = (const float*)d_in[0];
    const float* Wg = (const float*)d_in[1];
    const float* bg = (const float*)d_in[2];
    const float* Ew = (const float*)d_in[3];
    float* out = (float*)d_out;

    char* ws = (char*)d_ws;
    int*    hdr   = (int*)(ws + OFF_HDR);
    float*  tokw  = (float*)(ws + OFF_TOKW);
    int*    lists = (int*)(ws + OFF_LISTS);
    ushort* xbuf  = (ushort*)(ws + OFF_XB);
    ushort* ewT   = (ushort*)(ws + OFF_EWT);
    ushort* ybuf  = (ushort*)(ws + OFF_YBUF);

    prep_kernel<<<256 + NGBLK, 256, 0, stream>>>(x, Wg, bg, Ew, ewT, hdr, lists, tokw, xbuf);
    expert_kernel<<<dim3(NGBLK / NSEG, NE), 256, 0, stream>>>(xbuf, ewT, hdr, lists, ybuf);
    combine_kernel<<<NTOK / 16, 256, 0, stream>>>(ybuf, tokw, out, out + (size_t)NTOK * DD);
}